// Round 11
// baseline (71.430 us; speedup 1.0000x reference)
//
#include <hip/hip_runtime.h>

#define N 2000
#define NCLS 21
#define MAXPC 50
#define MAXPI 100
#define IOU_THR 0.7f

typedef unsigned long long u64;
typedef unsigned int u32;

// monotone float -> uint32 map (order-preserving, incl. negatives)
__device__ __forceinline__ u32 sortable(float s) {
    u32 u = __float_as_uint(s);
    return ((int)u < 0) ? ~u : (u | 0x80000000u);
}

// decode one box on the fly (bit-identical to reference formula)
__device__ __forceinline__ float4 decode_one(const float* __restrict__ rpn,
                                             const float* __restrict__ deltas, int i) {
    float4 p = ((const float4*)rpn)[i];
    float4 d = ((const float4*)deltas)[i];
    float h = p.z - p.x, w = p.w - p.y;
    float cy = p.x + 0.5f * h, cx = p.y + 0.5f * w;
    float pcy = d.x * h + cy;
    float pcx = d.y * w + cx;
    float ph = h * expf(d.z);
    float pw = w * expf(d.w);
    return make_float4(pcy - 0.5f * ph, pcx - 0.5f * pw, pcy + 0.5f * ph, pcx + 0.5f * pw);
}

__device__ __forceinline__ float iou_vs(float4 b, float ar,
                                        float kx, float ky, float kz, float kw) {
    float ka = (kz - kx) * (kw - ky);
    float iy1 = fmaxf(b.x, kx), ix1 = fmaxf(b.y, ky);
    float iy2 = fminf(b.z, kz), ix2 = fminf(b.w, kw);
    float inter = fmaxf(iy2 - iy1, 0.f) * fmaxf(ix2 - ix1, 0.f);
    return inter / fmaxf(ar + ka - inter, 1e-8f);
}

// ---------------- K1: spread stable sort (r4-proven, unchanged) ----------------
__global__ void sort_kernel(const float* __restrict__ score, int* __restrict__ order) {
    __shared__ __align__(16) u64 skey[N];
    int c = blockIdx.x;
    for (int i = threadIdx.x; i < N; i += blockDim.x) {
        u32 u = sortable(score[i * NCLS + c]);
        skey[i] = ((u64)u << 32) | (u32)(~i);
    }
    __syncthreads();
    int i = blockIdx.y * 64 + (threadIdx.x >> 2);
    int q = threadIdx.x & 3;
    if (i < N) {
        u64 ki = skey[i];
        const ulonglong2* s2 = (const ulonglong2*)skey;
        int r = 0;
        int jj0 = q * 250;
#pragma unroll 4
        for (int jj = jj0; jj < jj0 + 250; jj++) {
            ulonglong2 v = s2[jj];
            r += (v.x > ki);
            r += (v.y > ki);
        }
        r += __shfl_xor(r, 1);
        r += __shfl_xor(r, 2);
        if (q == 0) order[c * N + r] = i;
    }
}

// ---------------- K2: NMS (16 waves x classes) + top-100, ONE block ----------
// Wave w runs greedy-bitmask NMS (r10-proven) for classes w, w+16 with NO
// intra-block barriers; candidates live in LDS. One __syncthreads, then all
// waves rank candidates via binary search. No device-scope atomics/fences,
// no global candidate round-trip, no persistent state.
__global__ void __launch_bounds__(1024, 1)
nms_topk_kernel(const float* __restrict__ rpn, const float* __restrict__ deltas,
                const float* __restrict__ score,
                const int* __restrict__ order,
                float* __restrict__ out) {
    __shared__ float4 kbox[NCLS][MAXPC];   // kept boxes per class   (16.8 KB)
    __shared__ float4 cbox[16][64];        // per-wave chunk boxes   (16 KB)
    __shared__ u64 candk[NCLS][MAXPC];     // candidate keys         (8.4 KB)
    __shared__ int scnt[NCLS];

    int tid = threadIdx.x;
    int w = tid >> 6, lane = tid & 63;

    // ---------- NMS: each wave owns classes w, w+16 ----------
    for (int cls = w; cls < NCLS; cls += 16) {
        int nk = 0;
        const int NCH = (N + 63) / 64;
        for (int chunk = 0; chunk < NCH && nk < MAXPC; chunk++) {
            int pos = chunk * 64 + lane;
            bool valid = pos < N;
            int oi = order[cls * N + (valid ? pos : (N - 1))];
            float4 bb = decode_one(rpn, deltas, oi);
            cbox[w][lane] = bb;
            float ar = (bb.z - bb.x) * (bb.w - bb.y);
            bool sup = !valid;
            for (int k = 0; k < nk; k++) {       // vs kept: uniform LDS read = bcast
                float4 kb = kbox[cls][k];
                sup = sup || (iou_vs(bb, ar, kb.x, kb.y, kb.z, kb.w) > IOU_THR);
            }
            // intra-chunk pairwise suppression bits (uniform LDS reads)
            u64 supby = 0;
#pragma unroll 4
            for (int j = 0; j < 64; j++) {
                float4 bj = cbox[w][j];
                supby |= (u64)(iou_vs(bb, ar, bj.x, bj.y, bj.z, bj.w) > IOU_THR) << j;
            }
            u64 alive = __ballot(!sup);
            // uniform greedy over the chunk (all values wave-uniform)
            for (int l = 0; l < 64 && nk < MAXPC; l++) {
                u64 col = __ballot((supby >> l) & 1);     // who l suppresses
                if ((alive >> l) & 1) {
                    if (lane == l) {
                        kbox[cls][nk] = bb;
                        u32 u = sortable(score[oi * NCLS + cls]);
                        candk[cls][nk] = ((u64)u << 32) | (u32)(~(cls * N + pos));
                    }
                    nk++;
                    alive &= ~(col & (~0ull << (l + 1)));
                }
            }
        }
        if (lane == 0) scnt[cls] = nk;
    }
    __syncthreads();

    // ---------- top-100: binary-search ranking over LDS candidates ----------
    int M = 0;
#pragma unroll
    for (int c2 = 0; c2 < NCLS; c2++) M += scnt[c2];

    for (int t = tid; t < NCLS * MAXPC; t += 1024) {
        int cc = t / MAXPC, k = t - cc * MAXPC;
        if (k >= scnt[cc]) continue;
        u64 ki = candk[cc][k];
        int r = k;                           // rank within own descending list
#pragma unroll
        for (int c2 = 0; c2 < NCLS; c2++) {
            if (c2 == cc) continue;
            int lo = 0, hi = scnt[c2];
            while (lo < hi) {                // count of keys[c2][*] > ki
                int mid = (lo + hi) >> 1;
                if (candk[c2][mid] > ki) lo = mid + 1; else hi = mid;
            }
            r += lo;
        }
        if (r < MAXPI) {
            int flat = (int)(~(u32)ki);
            int pos = flat - cc * N;
            int oi = order[cc * N + pos];
            float4 bb = decode_one(rpn, deltas, oi);
            out[r * 4 + 0] = bb.x;
            out[r * 4 + 1] = bb.y;
            out[r * 4 + 2] = bb.z;
            out[r * 4 + 3] = bb.w;
            out[4 * MAXPI + r] = (float)cc;
        }
    }
    // rare path: M<100 -> fill with NEG entries, smallest flat first (class 0
    // positions; among pos 0..149 at most 50 kept -> >=100 invalid slots).
    if (tid == 0 && M < MAXPI) {
        int m = M;
        int cnt0 = scnt[0];
        for (int pos = 0; pos < 150 && m < MAXPI; pos++) {
            bool kept = false;
            for (int k = 0; k < cnt0; k++)
                if ((int)(~(u32)candk[0][k]) == pos) { kept = true; break; }
            if (!kept) {
                int oi = order[pos];
                float4 bb = decode_one(rpn, deltas, oi);
                out[m * 4 + 0] = bb.x;
                out[m * 4 + 1] = bb.y;
                out[m * 4 + 2] = bb.z;
                out[m * 4 + 3] = bb.w;
                out[4 * MAXPI + m] = 0.0f;
                m++;
            }
        }
    }
}

extern "C" void kernel_launch(void* const* d_in, const int* in_sizes, int n_in,
                              void* d_out, int out_size, void* d_ws, size_t ws_size,
                              hipStream_t stream) {
    const float* rpn    = (const float*)d_in[0];  // [2000,4]
    const float* deltas = (const float*)d_in[1];  // [2000,4]
    const float* score  = (const float*)d_in[2];  // [2000,21]
    float* out = (float*)d_out;                   // 400 box floats + 100 cls

    int* order = (int*)d_ws;                      // 168000 B

    sort_kernel<<<dim3(NCLS, 32), 256, 0, stream>>>(score, order);
    nms_topk_kernel<<<1, 1024, 0, stream>>>(rpn, deltas, score, order, out);
}

// Round 12
// 53.433 us; speedup vs baseline: 1.3368x; 1.3368x over previous
//
#include <hip/hip_runtime.h>

#define N 2000
#define NCLS 21
#define MAXPC 50
#define MAXPI 100
#define IOU_THR 0.7f
#define TSEL 256            // min candidates selected by histogram threshold
#define NBUCK 4096          // 12-bit buckets of the sortable u32 key

typedef unsigned long long u64;
typedef unsigned int u32;

// monotone float -> uint32 map (order-preserving, incl. negatives)
__device__ __forceinline__ u32 sortable(float s) {
    u32 u = __float_as_uint(s);
    return ((int)u < 0) ? ~u : (u | 0x80000000u);
}

// decode one box on the fly (bit-identical to reference formula)
__device__ __forceinline__ float4 decode_one(const float* __restrict__ rpn,
                                             const float* __restrict__ deltas, int i) {
    float4 p = ((const float4*)rpn)[i];
    float4 d = ((const float4*)deltas)[i];
    float h = p.z - p.x, w = p.w - p.y;
    float cy = p.x + 0.5f * h, cx = p.y + 0.5f * w;
    float pcy = d.x * h + cy;
    float pcx = d.y * w + cx;
    float ph = h * expf(d.z);
    float pw = w * expf(d.w);
    return make_float4(pcy - 0.5f * ph, pcx - 0.5f * pw, pcy + 0.5f * ph, pcx + 0.5f * pw);
}

__device__ __forceinline__ float iou_vs(float4 b, float ar,
                                        float kx, float ky, float kz, float kw) {
    float ka = (kz - kx) * (kw - ky);
    float iy1 = fmaxf(b.x, kx), ix1 = fmaxf(b.y, ky);
    float iy2 = fminf(b.z, kz), ix2 = fminf(b.w, kw);
    float inter = fmaxf(iy2 - iy1, 0.f) * fmaxf(ix2 - ix1, 0.f);
    return inter / fmaxf(ar + ka - inter, 1e-8f);
}

// ---------------- K1: histogram top-rank + NMS, one block per class ----------
// Replaces the N^2 rank sort (~4M u64 compares/class, inferred ~35us wall)
// with: 12-bit histogram -> threshold bucket for rank>=TSEL -> exact rank of
// only the ~TSEL+bucket candidates (C^2 ~ 0.15M compares). NMS (r10-proven
// bitmask greedy) consumes only top positions, so candidates suffice; exact
// fallback (full in-block rank) guards pathological suppression. No
// cross-block sync anywhere.
__global__ void __launch_bounds__(256, 1)
sortnms_kernel(const float* __restrict__ rpn, const float* __restrict__ deltas,
               const float* __restrict__ score,
               int* __restrict__ order,        // [NCLS][N] (top C ranks written)
               int* __restrict__ keep_pos,     // [NCLS][MAXPC]
               int* __restrict__ keep_cnt,     // [NCLS]
               u64* __restrict__ cand_key) {   // [NCLS][MAXPC]
    __shared__ u32 key[N];                       // 8000 B
    __shared__ u32 hist[NBUCK];                  // 16384 B
    __shared__ __align__(16) u64 cand[N + 1];    // 16008 B (supports full fallback)
    __shared__ int sorder[N];                    // 8000 B
    __shared__ int pp[2][256];                   // 2048 B
    __shared__ float4 cbox[64];                  // 1024 B
    __shared__ float4 kbox[MAXPC];               // 800 B
    __shared__ int s_bstar, s_ctot, s_cc, s_nk;

    int c = blockIdx.x, tid = threadIdx.x;

    // ---- histogram of sortable keys (top 12 bits) ----
    for (int t = tid; t < NBUCK; t += 256) hist[t] = 0;
    if (tid == 0) s_cc = 0;
    __syncthreads();
    for (int i = tid; i < N; i += 256) {
        u32 u = sortable(score[i * NCLS + c]);
        key[i] = u;
        atomicAdd(&hist[u >> 20], 1);
    }
    __syncthreads();

    // ---- suffix-scan to find threshold bucket b* (largest b with cum>=TSEL) ----
    {
        int s = 0;
        int b0 = tid * 16;
        for (int b = b0; b < b0 + 16; b++) s += hist[b];
        pp[0][tid] = s;
        __syncthreads();
        int src = 0;
        for (int d = 1; d < 256; d <<= 1) {
            int v = pp[src][tid] + ((tid + d < 256) ? pp[src][tid + d] : 0);
            pp[src ^ 1][tid] = v;
            src ^= 1;
            __syncthreads();
        }
        int suf = pp[src][tid];                          // cum from chunk tid up
        int sufn = (tid < 255) ? pp[src][tid + 1] : 0;
        if (suf >= TSEL && sufn < TSEL) {                // unique thread (suf monotone)
            int cum = sufn;
            int b = tid * 16 + 15;
            for (; b >= tid * 16; b--) {
                cum += hist[b];
                if (cum >= TSEL) break;
            }
            s_bstar = b;
            s_ctot = cum;
        }
    }
    __syncthreads();
    int bstar = s_bstar;
    int C = s_ctot;                                      // TSEL <= C <= N

    // ---- compact candidates (bucket >= b*), unordered ----
    for (int i = tid; i < N; i += 256) {
        u32 u = key[i];
        if ((int)(u >> 20) >= bstar) {
            int s = atomicAdd(&s_cc, 1);
            cand[s] = ((u64)u << 32) | (u32)(~i);
        }
    }
    __syncthreads();                                     // s_cc == C

    bool full = false;
    while (true) {
        if (full) {                                      // pathological fallback: all rows
            for (int i = tid; i < N; i += 256)
                cand[i] = ((u64)key[i] << 32) | (u32)(~i);
            C = N;
            __syncthreads();
        }
        // ---- exact rank among candidates: 4 lanes per element ----
        if (tid == 0 && (C & 1)) cand[C] = 0ull;         // pad for pair reads
        __syncthreads();
        {
            int q = tid & 3;
            int npair = (C + 1) >> 1;
            int qn = (npair + 3) >> 2;
            int lo = q * qn, hi = min(lo + qn, npair);
            const ulonglong2* c2 = (const ulonglong2*)cand;
            for (int e = (tid >> 2); e < C; e += 64) {
                u64 ke = cand[e];
                int r = 0;
                for (int p = lo; p < hi; p++) {          // uniform LDS reads (4 addrs/wave)
                    ulonglong2 v = c2[p];
                    r += (v.x > ke);
                    r += (v.y > ke);
                }
                r += __shfl_xor(r, 1);
                r += __shfl_xor(r, 2);
                if (q == 0) {
                    int i = (int)(~(u32)ke);
                    sorder[r] = i;
                    order[c * N + r] = i;
                }
            }
        }
        __syncthreads();

        // ---- NMS on wave 0 over sorted candidates (bitmask greedy, r10) ----
        if (tid < 64) {
            int lane = tid;
            int nk = 0;
            int NCH = (C + 63) >> 6;
            for (int chunk = 0; chunk < NCH && nk < MAXPC; chunk++) {
                int pos = chunk * 64 + lane;
                bool valid = pos < C;
                int oi = sorder[valid ? pos : 0];
                float4 bb = decode_one(rpn, deltas, oi);
                cbox[lane] = bb;
                float ar = (bb.z - bb.x) * (bb.w - bb.y);
                bool sup = !valid;
                for (int k = 0; k < nk; k++) {           // vs kept: uniform LDS = bcast
                    float4 kb = kbox[k];
                    sup = sup || (iou_vs(bb, ar, kb.x, kb.y, kb.z, kb.w) > IOU_THR);
                }
                u64 supby = 0;
#pragma unroll 4
                for (int j = 0; j < 64; j++) {           // uniform LDS = broadcast
                    float4 bj = cbox[j];
                    supby |= (u64)(iou_vs(bb, ar, bj.x, bj.y, bj.z, bj.w) > IOU_THR) << j;
                }
                u64 alive = __ballot(!sup);
                for (int l = 0; l < 64 && nk < MAXPC; l++) {
                    u64 col = __ballot((supby >> l) & 1);
                    if ((alive >> l) & 1) {
                        if (lane == l) {
                            kbox[nk] = bb;
                            keep_pos[c * MAXPC + nk] = pos;
                            cand_key[c * MAXPC + nk] =
                                ((u64)key[oi] << 32) | (u32)(~(c * N + pos));
                        }
                        nk++;
                        alive &= ~(col & (~0ull << (l + 1)));
                    }
                }
            }
            if (lane == 0) s_nk = nk;
        }
        __syncthreads();
        if (s_nk >= MAXPC || C >= N) {                   // complete (normal path)
            if (tid == 0) keep_cnt[c] = s_nk;
            break;
        }
        full = true;                                     // never taken on real data
        __syncthreads();
    }
}

// ---------------- K2: top-100 via per-class binary-search ranking (r4) -------
__global__ void topk_kernel(const float* __restrict__ rpn,
                            const float* __restrict__ deltas,
                            const int* __restrict__ order,
                            const int* __restrict__ keep_pos,
                            const int* __restrict__ keep_cnt,
                            const u64* __restrict__ cand_key,
                            float* __restrict__ out) {
    __shared__ u64 keys[NCLS][MAXPC];
    __shared__ int cnt[NCLS];
    int c = blockIdx.x;
    int lane = threadIdx.x;
    for (int t = lane; t < NCLS * MAXPC; t += 64)
        keys[t / MAXPC][t % MAXPC] = cand_key[t];
    if (lane < NCLS) cnt[lane] = keep_cnt[lane];
    __syncthreads();

    int M = 0;
#pragma unroll
    for (int cc = 0; cc < NCLS; cc++) M += cnt[cc];

    if (lane < cnt[c]) {
        u64 ki = keys[c][lane];
        int r = lane;                        // rank within own (descending) list
#pragma unroll
        for (int cc = 0; cc < NCLS; cc++) {
            if (cc == c) continue;
            int lo = 0, hi = cnt[cc];
            while (lo < hi) {                // count of keys[cc][*] > ki
                int mid = (lo + hi) >> 1;
                if (keys[cc][mid] > ki) lo = mid + 1; else hi = mid;
            }
            r += lo;
        }
        if (r < MAXPI) {
            int flat = (int)(~(u32)ki);
            int pos = flat - c * N;
            int oi = order[c * N + pos];
            float4 b = decode_one(rpn, deltas, oi);
            out[r * 4 + 0] = b.x;
            out[r * 4 + 1] = b.y;
            out[r * 4 + 2] = b.z;
            out[r * 4 + 3] = b.w;
            out[4 * MAXPI + r] = (float)c;
        }
    }

    // rare path: M<100 -> fill with NEG entries, smallest flat first (class 0
    // positions; among pos 0..149 at most 50 kept -> >=100 invalid slots;
    // order[0..149] always written since C>=TSEL=256).
    if (c == 0 && lane == 0 && M < MAXPI) {
        int m = M;
        int cnt0 = cnt[0];
        for (int pos = 0; pos < 150 && m < MAXPI; pos++) {
            bool validp = false;
            for (int k = 0; k < cnt0; k++)
                if (keep_pos[k] == pos) { validp = true; break; }
            if (!validp) {
                int oi = order[pos];
                float4 b = decode_one(rpn, deltas, oi);
                out[m * 4 + 0] = b.x;
                out[m * 4 + 1] = b.y;
                out[m * 4 + 2] = b.z;
                out[m * 4 + 3] = b.w;
                out[4 * MAXPI + m] = 0.0f;
                m++;
            }
        }
    }
}

extern "C" void kernel_launch(void* const* d_in, const int* in_sizes, int n_in,
                              void* d_out, int out_size, void* d_ws, size_t ws_size,
                              hipStream_t stream) {
    const float* rpn    = (const float*)d_in[0];  // [2000,4]
    const float* deltas = (const float*)d_in[1];  // [2000,4]
    const float* score  = (const float*)d_in[2];  // [2000,21]
    float* out = (float*)d_out;                   // 400 box floats + 100 cls

    char* ws = (char*)d_ws;
    int*   order    = (int*)(ws);                 // 168000 B
    u64*   candk    = (u64*)(ws + 168000);        // 8400 B (8-aligned)
    int*   keep_pos = (int*)(ws + 176400);        // 4200 B
    int*   keep_cnt = (int*)(ws + 180600);        // 84 B

    sortnms_kernel<<<NCLS, 256, 0, stream>>>(rpn, deltas, score, order,
                                             keep_pos, keep_cnt, candk);
    topk_kernel<<<NCLS, 64, 0, stream>>>(rpn, deltas, order,
                                         keep_pos, keep_cnt, candk, out);
}